// Round 16
// baseline (200.153 us; speedup 1.0000x reference)
//
#include <hip/hip_runtime.h>
#include <hip/hip_bf16.h>
#include <math.h>

#define BB 2
#define NN 2048
#define KK 256
#define DD 768
#define HH 150
#define LL 11
#define NBINS 10

#define KP 160          // padded K/N for MFMA tiles
#define WP 40           // staged k-slice row stride in shorts (proj)
#define GWP 136         // gate K-step-128 row stride in shorts
#define BPAD 264        // 256-i row stride in shorts (ctxt staging)

typedef __attribute__((ext_vector_type(8))) short short8;
typedef __attribute__((ext_vector_type(4))) short s16x4;
typedef __attribute__((ext_vector_type(4))) float f32x4;

#define AS_GLOBAL const __attribute__((address_space(1))) void*
#define AS_LDS __attribute__((address_space(3))) void*

__device__ inline unsigned bf2u(float lo, float hi) {
  union { __hip_bfloat162 b; unsigned u; } cv;
  cv.b = __float22bfloat162_rn(make_float2(lo, hi));
  return cv.u;
}
__device__ inline short bf1(float x) {
  union { __hip_bfloat16 b; short s; } cv;
  cv.b = __float2bfloat16(x);
  return cv.s;
}
__device__ inline float ubf(short b) {          // bf16 bits -> f32 (exact)
  return __uint_as_float(((unsigned)(unsigned short)b) << 16);
}

// ---------------- merged one-shot prep ----------------
#define PRE_PREP 110
#define PRE_CVT  192
#define PRE_TRGW 1152
#define PRE_TRWLR 240
#define PRE_TRUPD 384
#define PRE_NB (PRE_PREP + PRE_CVT + PRE_TRGW + PRE_TRWLR + PRE_TRUPD)

__global__ __launch_bounds__(256) void k_pre(
    const float* __restrict__ w_h, const float* __restrict__ w_out,
    short* __restrict__ wt, short* __restrict__ wo,
    const float* __restrict__ upd_in, short* __restrict__ updbf,
    const float* __restrict__ gate_w, short* __restrict__ gwt,
    const float* __restrict__ w_left, const float* __restrict__ w_right,
    short* __restrict__ wlrt, short* __restrict__ updT)
{
  __shared__ float tile[32][33];
  int bid = blockIdx.x;
  int t = threadIdx.x;

  if (bid < PRE_PREP) {
    int idx = bid * 256 + t;
    if (idx < KP * KP) {
      int n = idx / KP, k = idx - n * KP;
      float v = (n < HH && k < HH) ? w_h[k * HH + n] : 0.f;
      wt[idx] = bf1(v);
    }
    int idx2 = idx - KP * KP;
    if (idx2 >= 0 && idx2 < 16 * KP) {
      int n = idx2 / KP, k = idx2 - n * KP;
      float v = (n < LL && k < HH) ? w_out[k * LL + n] : 0.f;
      wo[idx2] = bf1(v);
    }
    return;
  }
  bid -= PRE_PREP;
  if (bid < PRE_CVT) {
    int idx = (bid * 256 + t) * 8;
    const float4* s4 = (const float4*)(upd_in + idx);
    float4 a = s4[0], c = s4[1];
    int4 pk;
    pk.x = (int)bf2u(a.x, a.y);
    pk.y = (int)bf2u(a.z, a.w);
    pk.z = (int)bf2u(c.x, c.y);
    pk.w = (int)bf2u(c.z, c.w);
    *(int4*)(updbf + idx) = pk;
    return;
  }
  bid -= PRE_CVT;
  if (bid < PRE_TRGW) {
    int kt = bid % 48, nt = bid / 48;
    int m0 = kt * 32, n0 = nt * 32;
    int tx = t & 31, ty = t >> 5;
    #pragma unroll
    for (int r = 0; r < 4; ++r)
      tile[ty + r * 8][tx] = gate_w[(size_t)(m0 + ty + r * 8) * DD + n0 + tx];
    __syncthreads();
    #pragma unroll
    for (int r = 0; r < 4; ++r)
      gwt[(size_t)(n0 + ty + r * 8) * (2 * DD) + m0 + tx] = bf1(tile[tx][ty + r * 8]);
    return;
  }
  bid -= PRE_TRGW;
  if (bid < PRE_TRWLR) {
    int kt = bid % 24, nt = bid / 24;
    int k0 = kt * 32, n0 = nt * 32;
    const float* src = (n0 >= KP) ? w_right : w_left;
    int col0 = n0 - (n0 >= KP ? KP : 0);
    int tx = t & 31, ty = t >> 5;
    #pragma unroll
    for (int r = 0; r < 4; ++r) {
      int col = col0 + tx;
      tile[ty + r * 8][tx] = (col < HH) ? src[(size_t)(k0 + ty + r * 8) * HH + col] : 0.f;
    }
    __syncthreads();
    #pragma unroll
    for (int r = 0; r < 4; ++r)
      wlrt[(size_t)(n0 + ty + r * 8) * DD + k0 + tx] = bf1(tile[tx][ty + r * 8]);
    return;
  }
  bid -= PRE_TRWLR;
  {
    int b = bid / 192;
    int r = bid - b * 192;
    int it = r & 7, dt = r >> 3;
    int i0 = it * 32, d0 = dt * 32;
    int tx = t & 31, ty = t >> 5;
    #pragma unroll
    for (int rr = 0; rr < 4; ++rr)
      tile[ty + rr * 8][tx] = upd_in[(size_t)(b * KK + i0 + ty + rr * 8) * DD + d0 + tx];
    __syncthreads();
    #pragma unroll
    for (int rr = 0; rr < 4; ++rr)
      updT[(size_t)(b * DD + d0 + ty + rr * 8) * KK + i0 + tx] = bf1(tile[tx][ty + rr * 8]);
  }
}

// ---------------- proj via MFMA + fused pruner-score blocks ----------------
__global__ __launch_bounds__(256) void k_projss(
    const short* __restrict__ updbf, const short* __restrict__ wlrt,
    const float* __restrict__ b_left, const float* __restrict__ b_right,
    const float* __restrict__ updf, const float* __restrict__ pr_w,
    const float* __restrict__ pr_b,
    float* __restrict__ left, float* __restrict__ right, float* __restrict__ ssv)
{
  __shared__ short As[64][WP];
  __shared__ short Bs[KP][WP];
  int bidx = blockIdx.x;
  int t = threadIdx.x;

  if (bidx >= 16) {     // pruner-score blocks
    int row = (bidx - 16) * 4 + (t >> 6);
    int l = t & 63;
    float s = 0.f;
    for (int d = l; d < DD; d += 64) s = fmaf(updf[(size_t)row * DD + d], pr_w[d], s);
    #pragma unroll
    for (int off = 32; off > 0; off >>= 1) s += __shfl_down(s, off);
    if (l == 0) ssv[row] = s + pr_b[0];
    return;
  }

  int rbk = bidx >> 1, half = bidx & 1;
  int row0 = rbk * 64;
  const short* wsrc = wlrt + (size_t)half * KP * DD;
  int l = t & 63, w = t >> 6, lr = l & 15, lg = l >> 4;
  int ar = t >> 2, ac = t & 3;
  int i1 = t + 256, i2 = t + 512;
  f32x4 acc[10];
  #pragma unroll
  for (int nt = 0; nt < 10; ++nt) acc[nt] = (f32x4){0.f, 0.f, 0.f, 0.f};

  short8 pa, pb0, pb1, pb2 = {};
  pa  = *(const short8*)(updbf + (size_t)(row0 + ar) * DD + ac * 8);
  pb0 = *(const short8*)(wsrc + (size_t)(t >> 2) * DD + (t & 3) * 8);
  pb1 = *(const short8*)(wsrc + (size_t)(i1 >> 2) * DD + (i1 & 3) * 8);
  if (i2 < 640) pb2 = *(const short8*)(wsrc + (size_t)(i2 >> 2) * DD + (i2 & 3) * 8);

  for (int ks = 0; ks < 24; ++ks) {
    __syncthreads();
    *(short8*)&As[ar][ac * 8] = pa;
    *(short8*)&Bs[t >> 2][(t & 3) * 8] = pb0;
    *(short8*)&Bs[i1 >> 2][(i1 & 3) * 8] = pb1;
    if (i2 < 640) *(short8*)&Bs[i2 >> 2][(i2 & 3) * 8] = pb2;
    __syncthreads();
    if (ks + 1 < 24) {
      int k0 = (ks + 1) * 32;
      pa  = *(const short8*)(updbf + (size_t)(row0 + ar) * DD + k0 + ac * 8);
      pb0 = *(const short8*)(wsrc + (size_t)(t >> 2) * DD + k0 + (t & 3) * 8);
      pb1 = *(const short8*)(wsrc + (size_t)(i1 >> 2) * DD + k0 + (i1 & 3) * 8);
      if (i2 < 640) pb2 = *(const short8*)(wsrc + (size_t)(i2 >> 2) * DD + k0 + (i2 & 3) * 8);
    }
    short8 a = *(short8*)&As[w * 16 + lr][lg * 8];
    #pragma unroll
    for (int nt = 0; nt < 10; ++nt) {
      short8 b = *(short8*)&Bs[nt * 16 + lr][lg * 8];
      acc[nt] = __builtin_amdgcn_mfma_f32_16x16x32_bf16(a, b, acc[nt], 0, 0, 0);
    }
  }
  const float* bias = half ? b_right : b_left;
  float* dst = half ? right : left;
  int rowb = row0 + w * 16 + lg * 4;
  #pragma unroll
  for (int nt = 0; nt < 10; ++nt) {
    int col = nt * 16 + lr;
    if (col < HH) {
      float bv = bias[col];
      #pragma unroll
      for (int q = 0; q < 4; ++q)
        dst[(size_t)(rowb + q) * HH + col] = acc[nt][q] + bv;
    }
  }
}

// ---------------- pair scores via MFMA (v10: 2 i-rows per block) ----------------
template <bool WPT>
__global__ __launch_bounds__(256, 3) void k_pair_mfma(
    const float* __restrict__ left, const float* __restrict__ right,
    const float* __restrict__ ss, const int* __restrict__ span_begin,
    const float* __restrict__ demb,
    const short* __restrict__ wt, const short* __restrict__ wo,
    const float* __restrict__ b_h, const float* __restrict__ b_out,
    const float* __restrict__ mask,
    float* __restrict__ rel, short* __restrict__ probsT)
{
  int bid = blockIdx.x;               // BB * 128 * 4 = 1024
  int b  = bid >> 9;
  int r2 = bid & 511;
  int i0 = (r2 >> 2) * 2;             // i = i0, i0+1
  int j0 = (r2 & 3) * 64;

  __shared__ short wtbuf[2][32 * KP];   // 20480 B; reused as h1 [64][160]
  __shared__ float demb_s[NBINS][KP];   // 6400 B zero-padded; reused as out_s f32[64][12]
  __shared__ float ssj_s[64];
  __shared__ float m_s[2][64];
  __shared__ int   bins0[64];
  __shared__ int   bins1[64];

  int t = threadIdx.x;
  int l = t & 63, w = t >> 6;
  int lr = l & 15, lg = l >> 4;

  auto dma_wt = [&](int s) {
    const short* src = wt + s * 5120;
    short* dst = &wtbuf[s & 1][0];
    #pragma unroll
    for (int c = 0; c < 3; ++c) {
      int idx = t + c * 256;
      if (idx < 640)
        __builtin_amdgcn_global_load_lds((AS_GLOBAL)(src + idx * 8),
                                         (AS_LDS)(dst + idx * 8), 16, 0, 0);
    }
  };

  // ---- phase 0: DMA slice 0; stage demb_s/bins/ssj/mask
  dma_wt(0);
  int sb0 = span_begin[b * KK + i0];
  int sb1 = span_begin[b * KK + i0 + 1];
  if (t < 64) {
    int sbj = span_begin[b * KK + j0 + t];
    int d0 = sbj - sb0; d0 = d0 < 0 ? -d0 : d0;
    int d1 = sbj - sb1; d1 = d1 < 0 ? -d1 : d1;
    bins0[t] = d0 > NBINS - 1 ? NBINS - 1 : d0;
    bins1[t] = d1 > NBINS - 1 ? NBINS - 1 : d1;
    ssj_s[t] = ss[b * KK + j0 + t];
    if (WPT) {
      m_s[0][t] = mask[((size_t)(b * KK + i0)) * KK + j0 + t];
      m_s[1][t] = mask[((size_t)(b * KK + i0 + 1)) * KK + j0 + t];
    }
  }
  for (int idx = t; idx < NBINS * KP; idx += 256) {
    int bn = idx / KP, k = idx - bn * KP;
    demb_s[bn][k] = (k < HH) ? demb[bn * HH + k] : 0.f;
  }
  __syncthreads();   // (A) DMA(0) drained + demb_s/bins ready

  // ---- build A-fragments for both i's
  int jr = w * 16 + lr;
  int bin0 = bins0[jr], bin1 = bins1[jr];
  const float* rrow  = right + (size_t)(b * KK + j0 + jr) * HH;
  const float* lrow0 = left + (size_t)(b * KK + i0) * HH;
  const float* lrow1 = lrow0 + HH;
  short8 afr0[5], afr1[5];
  #pragma unroll
  for (int ks = 0; ks < 5; ++ks) {
    unsigned pk0[4], pk1[4];
    #pragma unroll
    for (int e = 0; e < 4; ++e) {
      int k = ks * 32 + lg * 8 + e * 2;
      if (k < HH - 1) {
        float2 rv = *(const float2*)(rrow + k);
        float2 d0 = *(const float2*)(&demb_s[bin0][k]);
        float2 d1 = *(const float2*)(&demb_s[bin1][k]);
        float2 l0 = *(const float2*)(lrow0 + k);
        float2 l1 = *(const float2*)(lrow1 + k);
        pk0[e] = bf2u(fmaxf(l0.x + d0.x + rv.x, 0.f), fmaxf(l0.y + d0.y + rv.y, 0.f));
        pk1[e] = bf2u(fmaxf(l1.x + d1.x + rv.x, 0.f), fmaxf(l1.y + d1.y + rv.y, 0.f));
      } else {
        pk0[e] = 0; pk1[e] = 0;
      }
    }
    int4 t0; t0.x = (int)pk0[0]; t0.y = (int)pk0[1]; t0.z = (int)pk0[2]; t0.w = (int)pk0[3];
    int4 t1; t1.x = (int)pk1[0]; t1.y = (int)pk1[1]; t1.z = (int)pk1[2]; t1.w = (int)pk1[3];
    afr0[ks] = *(short8*)&t0;
    afr1[ks] = *(short8*)&t1;
  }

  // ---- GEMM1: 5 slices, each B-fragment feeds both i's
  f32x4 acc0[10], acc1[10];
  #pragma unroll
  for (int m = 0; m < 10; ++m) {
    acc0[m] = (f32x4){0.f, 0.f, 0.f, 0.f};
    acc1[m] = (f32x4){0.f, 0.f, 0.f, 0.f};
  }

  #pragma unroll
  for (int s = 0; s < 5; ++s) {
    if (s > 0) __syncthreads();     // drain DMA(s); prior reads of buf[(s+1)&1] done
    if (s + 1 < 5) dma_wt(s + 1);
    const short* bufp = &wtbuf[s & 1][0];
    #pragma unroll
    for (int ks = 0; ks < 5; ++ks) {
      #pragma unroll
      for (int ntp = 0; ntp < 2; ++ntp) {
        short8 bf = *(const short8*)(bufp + (ntp * 16 + lr) * KP + ks * 32 + lg * 8);
        acc0[s * 2 + ntp] = __builtin_amdgcn_mfma_f32_16x16x32_bf16(afr0[ks], bf, acc0[s * 2 + ntp], 0, 0, 0);
        acc1[s * 2 + ntp] = __builtin_amdgcn_mfma_f32_16x16x32_bf16(afr1[ks], bf, acc1[s * 2 + ntp], 0, 0, 0);
      }
    }
  }
  __syncthreads();   // (B) all wt reads done -> wtbuf reusable as h1

  short* h1 = &wtbuf[0][0];
  float* out_s = (float*)&demb_s[0][0];

  #pragma unroll
  for (int ii = 0; ii < 2; ++ii) {
    if (ii > 0) __syncthreads();    // out_s reads + h1 reads of prev i done

    // ---- h1 = relu(acc + b_h)
    #pragma unroll
    for (int m = 0; m < 10; ++m) {
      int col = (m >> 1) * 32 + (m & 1) * 16 + lr;
      float bh = (col < HH) ? b_h[col] : 0.f;
      f32x4 av = (ii == 0) ? acc0[m] : acc1[m];
      #pragma unroll
      for (int q = 0; q < 4; ++q) {
        int row = w * 16 + lg * 4 + q;
        h1[row * KP + col] = bf1(fmaxf(av[q] + bh, 0.f));
      }
    }
    __syncthreads();                // h1 ready

    // ---- GEMM2: h1 @ wo (wo loaded from L2 here, not prefetched)
    f32x4 acc2 = (f32x4){0.f, 0.f, 0.f, 0.f};
    #pragma unroll
    for (int ks = 0; ks < 5; ++ks) {
      short8 a = *(const short8*)(h1 + (w * 16 + lr) * KP + ks * 32 + lg * 8);
      short8 bfw = *(const short8*)(wo + lr * KP + ks * 32 + lg * 8);
      acc2 = __builtin_amdgcn_mfma_f32_16x16x32_bf16(a, bfw, acc2, 0, 0, 0);
    }

    // ---- epilogue into out_s, then line-complete stores
    float ssi = ss[b * KK + i0 + ii];
    if (lr < LL) {
      float bo = b_out[lr];
      #pragma unroll
      for (int q = 0; q < 4; ++q) {
        int row = w * 16 + lg * 4 + q;
        out_s[row * 12 + lr] = acc2[q] + bo + ssi + ssj_s[row];
      }
    }
    __syncthreads();                // out_s ready (also: GEMM2 h1 reads done)
    if (!WPT) {
      size_t base = ((size_t)(b * KK + i0 + ii) * KK + j0) * LL;
      for (int idx = t; idx < 64 * LL; idx += 256) {
        int j = idx / LL, ll2 = idx - j * LL;
        rel[base + idx] = out_s[j * 12 + ll2];
      }
    } else {
      for (int idx = t; idx < 64 * LL; idx += 256) {
        int j = idx / LL, ll2 = idx - j * LL;
        float v = fmaxf(out_s[j * 12 + ll2], 0.f) * m_s[ii][j];
        probsT[(((size_t)(b * LL + ll2)) * KK + j0 + j) * KK + i0 + ii] = bf1(v);
      }
    }
  }
}

// ---------------- ctxt via MFMA (bf16-only output; d-tile 32 -> 384 blocks) ----------------
__global__ __launch_bounds__(256) void k_ctxt_mfma(
    const short* __restrict__ probsT, const short* __restrict__ updT,
    const float* __restrict__ a_w, const float* __restrict__ span_len,
    short* __restrict__ ctxbf)
{
  int bidx = blockIdx.x;              // B * 8 * 24 = 384
  int b = bidx / 192;
  int r = bidx - b * 192;
  int jt = r / 24, dt = r - jt * 24;
  int j0 = jt * 32, d0 = dt * 32;

  __shared__ short Bs[32][BPAD];
  __shared__ short As[32][BPAD];

  int t = threadIdx.x, l = t & 63, w = t >> 6, lr = l & 15, lg = l >> 4;
  int wr = w >> 1, wc = w & 1;

  for (int s = 0; s < 4; ++s) {
    int idx = t + s * 256;
    int row = idx >> 5, c = idx & 31;
    *(short8*)&Bs[row][c * 8] =
        *(const short8*)(updT + ((size_t)(b * DD + d0 + row)) * KK + c * 8);
  }

  short8 pa[4];
  #pragma unroll
  for (int s = 0; s < 4; ++s) {
    int idx = t + s * 256;
    int row = idx >> 5, c = idx & 31;
    pa[s] = *(const short8*)(probsT + (((size_t)(b * LL + 0)) * KK + j0 + row) * KK + c * 8);
  }

  f32x4 accF = (f32x4){0.f, 0.f, 0.f, 0.f};

  for (int ll = 0; ll < LL; ++ll) {
    __syncthreads();
    #pragma unroll
    for (int s = 0; s < 4; ++s) {
      int idx = t + s * 256;
      int row = idx >> 5, c = idx & 31;
      *(short8*)&As[row][c * 8] = pa[s];
    }
    if (ll + 1 < LL) {
      #pragma unroll
      for (int s = 0; s < 4; ++s) {
        int idx = t + s * 256;
        int row = idx >> 5, c = idx & 31;
        pa[s] = *(const short8*)(probsT + (((size_t)(b * LL + ll + 1)) * KK + j0 + row) * KK + c * 8);
      }
    }
    float awl = a_w[ll * DD + d0 + wc * 16 + lr];
    __syncthreads();

    f32x4 accL = (f32x4){0.f, 0.f, 0.f, 0.f};
    #pragma unroll
    for (int ks = 0; ks < 8; ++ks) {
      short8 a = *(short8*)&As[wr * 16 + lr][ks * 32 + lg * 8];
      short8 bf = *(short8*)&Bs[wc * 16 + lr][ks * 32 + lg * 8];
      accL = __builtin_amdgcn_mfma_f32_16x16x32_bf16(a, bf, accL, 0, 0, 0);
    }
    #pragma unroll
    for (int q = 0; q < 4; ++q)
      accF[q] = fmaf(awl, accL[q], accF[q]);
  }

  float inv = 1.f / span_len[b];
  int rowb = j0 + wr * 16 + lg * 4;
  int col = d0 + wc * 16 + lr;
  #pragma unroll
  for (int q = 0; q < 4; ++q) {
    size_t off = (size_t)(b * KK + rowb + q) * DD + col;
    ctxbf[off] = bf1(accF[q] * inv);
  }
}

// ---------------- gate via MFMA (K-step 128, bf16 ctxt blend, optional fused scatter) ----------------
template <bool LAST>
__global__ __launch_bounds__(256) void k_gate_mfma(
    const short* __restrict__ updbf, const short* __restrict__ ctxbf,
    const short* __restrict__ gwt, const float* __restrict__ gate_b,
    const float* __restrict__ updr, float* __restrict__ updw,
    short* __restrict__ nxtbf, short* __restrict__ updT,
    const int* __restrict__ prune, const float* __restrict__ span_len,
    float* __restrict__ out_all)
{
  int rb = blockIdx.x / 12, cb = blockIdx.x - rb * 12;
  int row0 = rb * 32, col0 = cb * 64;
  __shared__ short As[32][GWP];
  __shared__ short Bs[64][GWP];
  int t = threadIdx.x, l = t & 63, w = t >> 6, lr = l & 15, lg = l >> 4;
  int wr = w >> 1, wc = w & 1;

  f32x4 acc[2];
  acc[0] = (f32x4){0.f, 0.f, 0.f, 0.f};
  acc[1] = (f32x4){0.f, 0.f, 0.f, 0.f};

  short8 pa[2], pb[4];
  #pragma unroll
  for (int s = 0; s < 2; ++s) {
    int idx = t + s * 256;
    pa[s] = *(const short8*)(updbf + (size_t)(row0 + (idx >> 4)) * DD + (idx & 15) * 8);
  }
  #pragma unroll
  for (int s = 0; s < 4; ++s) {
    int idx = t + s * 256;
    pb[s] = *(const short8*)(gwt + (size_t)(col0 + (idx >> 4)) * (2 * DD) + (idx & 15) * 8);
  }

  for (int ph = 0; ph < 12; ++ph) {
    __syncthreads();
    #pragma unroll
    for (int s = 0; s < 2; ++s) {
      int idx = t + s * 256;
      *(short8*)&As[idx >> 4][(idx & 15) * 8] = pa[s];
    }
    #pragma unroll
    for (int s = 0; s < 4; ++s) {
      int idx = t + s * 256;
      *(short8*)&Bs[idx >> 4][(idx & 15) * 8] = pb[s];
    }
    if (ph + 1 < 12) {
      int k0 = (ph + 1) * 128;
      #pragma unroll
      for (int s = 0; s < 2; ++s) {
        int idx = t + s * 256;
        int ka = k0 + (idx & 15) * 8;
        const short* asrc = (ka < DD) ? (updbf + (size_t)(row0 + (idx >> 4)) * DD + ka)
                                      : (ctxbf + (size_t)(row0 + (idx >> 4)) * DD + ka - DD);
        pa[s] = *(const short8*)asrc;
      }
      #pragma unroll
      for (int s = 0; s < 4; ++s) {
        int idx = t + s * 256;
        pb[s] = *(const short8*)(gwt + (size_t)(col0 + (idx >> 4)) * (2 * DD) + k0 + (idx & 15) * 8);
      }
    }
    __syncthreads();
    #pragma unroll
    for (int ksub = 0; ksub < 4; ++ksub) {
      short8 a = *(short8*)&As[wr * 16 + lr][ksub * 32 + lg * 8];
      #pragma unroll
      for (int nt = 0; nt < 2; ++nt) {
        short8 bf = *(short8*)&Bs[wc * 32 + nt * 16 + lr][ksub * 32 + lg * 8];
        acc[nt] = __builtin_amdgcn_mfma_f32_16x16x32_bf16(a, bf, acc[nt], 0, 0, 0);
      }
    }
  }
  int rowb = row0 + wr * 16 + lg * 4;
  int bb = rowb >> 8, ii = rowb & 255;
  #pragma unroll
  for (int nt = 0; nt < 2; ++nt) {
    int col = col0 + wc * 32 + nt * 16 + lr;
    float gb = gate_b[col];
    s16x4 tw;
    #pragma unroll
    for (int q = 0; q < 4; ++q) {
      size_t off = (size_t)(rowb + q) * DD + col;
      float x = acc[nt][q] + gb;
      float g = 1.f / (1.f + expf(-x));
      float cv = ubf(ctxbf[off]);
      float o = g * updr[off] + (1.f - g) * cv;
      updw[off] = o;
      short bv = bf1(o);
      nxtbf[off] = bv;
      tw[q] = bv;
      if (LAST) {
        int iq = ii + q;
        if ((float)iq < span_len[bb]) {
          int dst = prune[bb * KK + iq];
          out_all[((size_t)(bb * NN + dst)) * DD + col] = o;
        }
      }
    }
    *(s16x4*)(updT + ((size_t)(bb * DD + col)) * KK + ii) = tw;
  }
}

extern "C" void kernel_launch(void* const* d_in, const int* in_sizes, int n_in,
                              void* d_out, int out_size, void* d_ws, size_t ws_size,
                              hipStream_t stream)
{
  (void)in_sizes; (void)n_in; (void)out_size; (void)ws_size;
  const float* all_span = (const float*)d_in[0];
  const float* upd_in   = (const float*)d_in[1];
  const float* mask     = (const float*)d_in[2];
  const float* span_len = (const float*)d_in[3];
  const int*   span_beg = (const int*)d_in[4];
  const int*   prune    = (const int*)d_in[6];
  const float* w_left   = (const float*)d_in[7];
  const float* b_left   = (const float*)d_in[8];
  const float* w_right  = (const float*)d_in[9];
  const float* b_right  = (const float*)d_in[10];
  const float* dist_emb = (const float*)d_in[11];
  const float* w_h      = (const float*)d_in[12];
  const float* b_h      = (const float*)d_in[13];
  const float* w_out    = (const float*)d_in[14];
  const float* b_out    = (const float*)d_in[15];
  const float* a_w      = (const float*)d_in[16];
  const float* gate_w   = (const float*)d_in[17];
  const float* gate_b   = (const float*)d_in[18];
  const float* pr_w     = (const float*)d_in[19];
  const float* pr_b     = (const float*)d_in[20];

  float* out_all = (float*)d_out;
  float* out_upd = out_all + (size_t)BB * NN * DD;
  float* out_rel = out_upd + (size_t)BB * KK * DD;

  float* ws     = (float*)d_ws;
  float* left   = ws;
  float* right  = left + (size_t)BB * KK * HH;
  float* ssv    = right + (size_t)BB * KK * HH + 64;
  short* wt_bf  = (short*)(ssv + (size_t)BB * KK);
  short* wo_bf  = wt_bf + KP * KP;
  short* updbf0 = wo_bf + 16 * KP;
  short* updbf1 = updbf0 + (size_t)BB * KK * DD;
  short* ctxbf  = updbf1 + (size_t)BB * KK * DD;
  short* gwt    = ctxbf + (size_t)BB * KK * DD;
  short* wlrt   = gwt + (size_t)DD * 2 * DD;
  short* probsT = wlrt + (size_t)2 * KP * DD;
  short* updT   = probsT + (size_t)BB * LL * KK * KK;

  hipMemcpyAsync(out_all, all_span, sizeof(float) * (size_t)BB * NN * DD,
                 hipMemcpyDeviceToDevice, stream);
  k_pre<<<PRE_NB, 256, 0, stream>>>(w_h, w_out, wt_bf, wo_bf, upd_in, updbf0,
                                    gate_w, gwt, w_left, w_right, wlrt, updT);

  k_projss<<<144, 256, 0, stream>>>(updbf0, wlrt, b_left, b_right, upd_in,
                                    pr_w, pr_b, left, right, ssv);
  k_pair_mfma<true><<<BB * (KK / 2) * 4, 256, 0, stream>>>(
      left, right, ssv, span_beg, dist_emb, wt_bf, wo_bf, b_h, b_out, mask,
      out_rel, probsT);

  for (int p = 0; p < 2; ++p) {
    short* cur_bf = (p == 0) ? updbf0 : updbf1;
    short* nxt_bf = (p == 0) ? updbf1 : updbf0;
    const float* updr = (p == 0) ? upd_in : out_upd;
    k_ctxt_mfma<<<BB * 8 * 24, 256, 0, stream>>>(probsT, updT, a_w, span_len, ctxbf);
    if (p == 0) {
      k_gate_mfma<false><<<16 * 12, 256, 0, stream>>>(
          cur_bf, ctxbf, gwt, gate_b, updr, out_upd, nxt_bf, updT,
          prune, span_len, out_all);
    } else {
      k_gate_mfma<true><<<16 * 12, 256, 0, stream>>>(
          cur_bf, ctxbf, gwt, gate_b, updr, out_upd, nxt_bf, updT,
          prune, span_len, out_all);
    }
    k_projss<<<144, 256, 0, stream>>>(nxt_bf, wlrt, b_left, b_right, out_upd,
                                      pr_w, pr_b, left, right, ssv);
    if (p == 0) {
      k_pair_mfma<true><<<BB * (KK / 2) * 4, 256, 0, stream>>>(
          left, right, ssv, span_beg, dist_emb, wt_bf, wo_bf, b_h, b_out, mask,
          out_rel, probsT);
    } else {
      k_pair_mfma<false><<<BB * (KK / 2) * 4, 256, 0, stream>>>(
          left, right, ssv, span_beg, dist_emb, wt_bf, wo_bf, b_h, b_out, mask,
          out_rel, probsT);
    }
  }
}

// Round 17
// 186.484 us; speedup vs baseline: 1.0733x; 1.0733x over previous
//
#include <hip/hip_runtime.h>
#include <hip/hip_bf16.h>
#include <math.h>

#define BB 2
#define NN 2048
#define KK 256
#define DD 768
#define HH 150
#define LL 11
#define NBINS 10

#define KP 160          // padded K/N for MFMA tiles
#define HS 152          // h1 row stride in shorts (cols>=152 aliased, killed by wo zeros)
#define WP 40           // staged k-slice row stride in shorts (proj)
#define GWP 136         // gate K-step-128 row stride in shorts
#define BPAD 264        // 256-i row stride in shorts (ctxt staging)

typedef __attribute__((ext_vector_type(8))) short short8;
typedef __attribute__((ext_vector_type(4))) short s16x4;
typedef __attribute__((ext_vector_type(4))) float f32x4;

#define AS_GLOBAL const __attribute__((address_space(1))) void*
#define AS_LDS __attribute__((address_space(3))) void*

__device__ inline unsigned bf2u(float lo, float hi) {
  union { __hip_bfloat162 b; unsigned u; } cv;
  cv.b = __float22bfloat162_rn(make_float2(lo, hi));
  return cv.u;
}
__device__ inline short bf1(float x) {
  union { __hip_bfloat16 b; short s; } cv;
  cv.b = __float2bfloat16(x);
  return cv.s;
}
__device__ inline float ubf(short b) {          // bf16 bits -> f32 (exact)
  return __uint_as_float(((unsigned)(unsigned short)b) << 16);
}

// ---------------- merged one-shot prep ----------------
#define PRE_PREP 110
#define PRE_CVT  192
#define PRE_TRGW 1152
#define PRE_TRWLR 240
#define PRE_TRUPD 384
#define PRE_NB (PRE_PREP + PRE_CVT + PRE_TRGW + PRE_TRWLR + PRE_TRUPD)

__global__ __launch_bounds__(256) void k_pre(
    const float* __restrict__ w_h, const float* __restrict__ w_out,
    short* __restrict__ wt, short* __restrict__ wo,
    const float* __restrict__ upd_in, short* __restrict__ updbf,
    const float* __restrict__ gate_w, short* __restrict__ gwt,
    const float* __restrict__ w_left, const float* __restrict__ w_right,
    short* __restrict__ wlrt, short* __restrict__ updT)
{
  __shared__ float tile[32][33];
  int bid = blockIdx.x;
  int t = threadIdx.x;

  if (bid < PRE_PREP) {
    int idx = bid * 256 + t;
    if (idx < KP * KP) {
      int n = idx / KP, k = idx - n * KP;
      float v = (n < HH && k < HH) ? w_h[k * HH + n] : 0.f;
      wt[idx] = bf1(v);
    }
    int idx2 = idx - KP * KP;
    if (idx2 >= 0 && idx2 < 16 * KP) {
      int n = idx2 / KP, k = idx2 - n * KP;
      float v = (n < LL && k < HH) ? w_out[k * LL + n] : 0.f;
      wo[idx2] = bf1(v);
    }
    return;
  }
  bid -= PRE_PREP;
  if (bid < PRE_CVT) {
    int idx = (bid * 256 + t) * 8;
    const float4* s4 = (const float4*)(upd_in + idx);
    float4 a = s4[0], c = s4[1];
    int4 pk;
    pk.x = (int)bf2u(a.x, a.y);
    pk.y = (int)bf2u(a.z, a.w);
    pk.z = (int)bf2u(c.x, c.y);
    pk.w = (int)bf2u(c.z, c.w);
    *(int4*)(updbf + idx) = pk;
    return;
  }
  bid -= PRE_CVT;
  if (bid < PRE_TRGW) {
    int kt = bid % 48, nt = bid / 48;
    int m0 = kt * 32, n0 = nt * 32;
    int tx = t & 31, ty = t >> 5;
    #pragma unroll
    for (int r = 0; r < 4; ++r)
      tile[ty + r * 8][tx] = gate_w[(size_t)(m0 + ty + r * 8) * DD + n0 + tx];
    __syncthreads();
    #pragma unroll
    for (int r = 0; r < 4; ++r)
      gwt[(size_t)(n0 + ty + r * 8) * (2 * DD) + m0 + tx] = bf1(tile[tx][ty + r * 8]);
    return;
  }
  bid -= PRE_TRGW;
  if (bid < PRE_TRWLR) {
    int kt = bid % 24, nt = bid / 24;
    int k0 = kt * 32, n0 = nt * 32;
    const float* src = (n0 >= KP) ? w_right : w_left;
    int col0 = n0 - (n0 >= KP ? KP : 0);
    int tx = t & 31, ty = t >> 5;
    #pragma unroll
    for (int r = 0; r < 4; ++r) {
      int col = col0 + tx;
      tile[ty + r * 8][tx] = (col < HH) ? src[(size_t)(k0 + ty + r * 8) * HH + col] : 0.f;
    }
    __syncthreads();
    #pragma unroll
    for (int r = 0; r < 4; ++r)
      wlrt[(size_t)(n0 + ty + r * 8) * DD + k0 + tx] = bf1(tile[tx][ty + r * 8]);
    return;
  }
  bid -= PRE_TRWLR;
  {
    int b = bid / 192;
    int r = bid - b * 192;
    int it = r & 7, dt = r >> 3;
    int i0 = it * 32, d0 = dt * 32;
    int tx = t & 31, ty = t >> 5;
    #pragma unroll
    for (int rr = 0; rr < 4; ++rr)
      tile[ty + rr * 8][tx] = upd_in[(size_t)(b * KK + i0 + ty + rr * 8) * DD + d0 + tx];
    __syncthreads();
    #pragma unroll
    for (int rr = 0; rr < 4; ++rr)
      updT[(size_t)(b * DD + d0 + ty + rr * 8) * KK + i0 + tx] = bf1(tile[tx][ty + rr * 8]);
  }
}

// ---------------- proj via MFMA + fused pruner-score blocks ----------------
__global__ __launch_bounds__(256) void k_projss(
    const short* __restrict__ updbf, const short* __restrict__ wlrt,
    const float* __restrict__ b_left, const float* __restrict__ b_right,
    const float* __restrict__ updf, const float* __restrict__ pr_w,
    const float* __restrict__ pr_b,
    float* __restrict__ left, float* __restrict__ right, float* __restrict__ ssv)
{
  __shared__ short As[64][WP];
  __shared__ short Bs[KP][WP];
  int bidx = blockIdx.x;
  int t = threadIdx.x;

  if (bidx >= 16) {     // pruner-score blocks
    int row = (bidx - 16) * 4 + (t >> 6);
    int l = t & 63;
    float s = 0.f;
    for (int d = l; d < DD; d += 64) s = fmaf(updf[(size_t)row * DD + d], pr_w[d], s);
    #pragma unroll
    for (int off = 32; off > 0; off >>= 1) s += __shfl_down(s, off);
    if (l == 0) ssv[row] = s + pr_b[0];
    return;
  }

  int rbk = bidx >> 1, half = bidx & 1;
  int row0 = rbk * 64;
  const short* wsrc = wlrt + (size_t)half * KP * DD;
  int l = t & 63, w = t >> 6, lr = l & 15, lg = l >> 4;
  int ar = t >> 2, ac = t & 3;
  int i1 = t + 256, i2 = t + 512;
  f32x4 acc[10];
  #pragma unroll
  for (int nt = 0; nt < 10; ++nt) acc[nt] = (f32x4){0.f, 0.f, 0.f, 0.f};

  short8 pa, pb0, pb1, pb2 = {};
  pa  = *(const short8*)(updbf + (size_t)(row0 + ar) * DD + ac * 8);
  pb0 = *(const short8*)(wsrc + (size_t)(t >> 2) * DD + (t & 3) * 8);
  pb1 = *(const short8*)(wsrc + (size_t)(i1 >> 2) * DD + (i1 & 3) * 8);
  if (i2 < 640) pb2 = *(const short8*)(wsrc + (size_t)(i2 >> 2) * DD + (i2 & 3) * 8);

  for (int ks = 0; ks < 24; ++ks) {
    __syncthreads();
    *(short8*)&As[ar][ac * 8] = pa;
    *(short8*)&Bs[t >> 2][(t & 3) * 8] = pb0;
    *(short8*)&Bs[i1 >> 2][(i1 & 3) * 8] = pb1;
    if (i2 < 640) *(short8*)&Bs[i2 >> 2][(i2 & 3) * 8] = pb2;
    __syncthreads();
    if (ks + 1 < 24) {
      int k0 = (ks + 1) * 32;
      pa  = *(const short8*)(updbf + (size_t)(row0 + ar) * DD + k0 + ac * 8);
      pb0 = *(const short8*)(wsrc + (size_t)(t >> 2) * DD + k0 + (t & 3) * 8);
      pb1 = *(const short8*)(wsrc + (size_t)(i1 >> 2) * DD + k0 + (i1 & 3) * 8);
      if (i2 < 640) pb2 = *(const short8*)(wsrc + (size_t)(i2 >> 2) * DD + k0 + (i2 & 3) * 8);
    }
    short8 a = *(short8*)&As[w * 16 + lr][lg * 8];
    #pragma unroll
    for (int nt = 0; nt < 10; ++nt) {
      short8 b = *(short8*)&Bs[nt * 16 + lr][lg * 8];
      acc[nt] = __builtin_amdgcn_mfma_f32_16x16x32_bf16(a, b, acc[nt], 0, 0, 0);
    }
  }
  const float* bias = half ? b_right : b_left;
  float* dst = half ? right : left;
  int rowb = row0 + w * 16 + lg * 4;
  #pragma unroll
  for (int nt = 0; nt < 10; ++nt) {
    int col = nt * 16 + lr;
    if (col < HH) {
      float bv = bias[col];
      #pragma unroll
      for (int q = 0; q < 4; ++q)
        dst[(size_t)(rowb + q) * HH + col] = acc[nt][q] + bv;
    }
  }
}

// ---------------- pair scores via MFMA (v11: 1 i/block, single-buffer wt, ~20.3KB LDS) ----------------
template <bool WPT>
__global__ __launch_bounds__(256, 4) void k_pair_mfma(
    const float* __restrict__ left, const float* __restrict__ right,
    const float* __restrict__ ss, const int* __restrict__ span_begin,
    const float* __restrict__ demb,
    const short* __restrict__ wt, const short* __restrict__ wo,
    const float* __restrict__ b_h, const float* __restrict__ b_out,
    const float* __restrict__ mask,
    float* __restrict__ rel, short* __restrict__ probsT)
{
  int bid = blockIdx.x;
  int b  = bid >> 10;
  int r2 = bid & 1023;
  int i  = r2 >> 2;
  int j0 = (r2 & 3) * 64;

  // 19472 B union: [wt slab 10240 | ld_s 6400 @10240] -> h1 [64][HS] -> out_s f32[64][12]
  __shared__ int4 smem[1217];
  __shared__ float ssj_s[64];
  __shared__ float m_s[64];
  __shared__ int   bins[64];

  short* wtslab = (short*)smem;
  float* ld_s   = (float*)((char*)smem + 10240);
  short* h1     = (short*)smem;
  float* out_s  = (float*)smem;

  int t = threadIdx.x;
  int l = t & 63, w = t >> 6;
  int lr = l & 15, lg = l >> 4;

  auto dma_wt = [&](int s) {
    const short* src = wt + s * 5120;
    #pragma unroll
    for (int c = 0; c < 3; ++c) {
      int idx = t + c * 256;
      if (idx < 640)
        __builtin_amdgcn_global_load_lds((AS_GLOBAL)(src + idx * 8),
                                         (AS_LDS)(wtslab + idx * 8), 16, 0, 0);
    }
  };

  // ---- phase 0: DMA slice 0; stage ld_s (left_i+demb, zero-padded), bins/ssj/mask
  dma_wt(0);
  int sbi = span_begin[b * KK + i];
  if (t < 64) {
    int d = span_begin[b * KK + j0 + t] - sbi; d = d < 0 ? -d : d;
    bins[t] = d > NBINS - 1 ? NBINS - 1 : d;
    ssj_s[t] = ss[b * KK + j0 + t];
    if (WPT) m_s[t] = mask[((size_t)(b * KK + i)) * KK + j0 + t];
  }
  {
    const float* lrow = left + (size_t)(b * KK + i) * HH;
    for (int idx = t; idx < NBINS * KP; idx += 256) {
      int bn = idx / KP, k = idx - bn * KP;
      ld_s[bn * KP + k] = (k < HH) ? (lrow[k] + demb[bn * HH + k]) : 0.f;
    }
  }
  __syncthreads();   // DMA(0) drained + ld_s/bins ready

  // ---- build A-fragments in registers
  int jr = w * 16 + lr;
  int binr = bins[jr];
  const float* rrow = right + (size_t)(b * KK + j0 + jr) * HH;
  const float* ldr = ld_s + binr * KP;
  short8 afr[5];
  #pragma unroll
  for (int ks = 0; ks < 5; ++ks) {
    unsigned pk[4];
    #pragma unroll
    for (int e = 0; e < 4; ++e) {
      int k = ks * 32 + lg * 8 + e * 2;
      float2 r2v = (k < HH - 1) ? *(const float2*)(rrow + k) : make_float2(0.f, 0.f);
      float2 lv = *(const float2*)(ldr + k);
      float v0 = fmaxf(lv.x + r2v.x, 0.f);
      float v1 = fmaxf(lv.y + r2v.y, 0.f);
      pk[e] = bf2u(v0, v1);
    }
    int4 tmp; tmp.x = (int)pk[0]; tmp.y = (int)pk[1]; tmp.z = (int)pk[2]; tmp.w = (int)pk[3];
    afr[ks] = *(short8*)&tmp;
  }

  // ---- GEMM1: 5 slices, single-buffered (TLP hides the DMA latency)
  f32x4 acc[10];
  #pragma unroll
  for (int m = 0; m < 10; ++m) acc[m] = (f32x4){0.f, 0.f, 0.f, 0.f};

  #pragma unroll
  for (int s = 0; s < 5; ++s) {
    if (s > 0) {
      __syncthreads();              // prior slice reads done
      dma_wt(s);
      __syncthreads();              // DMA drained
    }
    #pragma unroll
    for (int ks = 0; ks < 5; ++ks) {
      short8 a = afr[ks];
      #pragma unroll
      for (int ntp = 0; ntp < 2; ++ntp) {
        short8 bf = *(const short8*)(wtslab + (ntp * 16 + lr) * KP + ks * 32 + lg * 8);
        acc[s * 2 + ntp] = __builtin_amdgcn_mfma_f32_16x16x32_bf16(a, bf, acc[s * 2 + ntp], 0, 0, 0);
      }
    }
  }
  __syncthreads();   // wt + ld_s reads done -> h1 region free

  // ---- h1 = relu(acc + b_h) -> bf16, stride HS (cols >=152 not written)
  #pragma unroll
  for (int m = 0; m < 10; ++m) {
    int col = (m >> 1) * 32 + (m & 1) * 16 + lr;
    float bh = (col < HH) ? b_h[col] : 0.f;
    if (m < 9 || lr < 8) {
      #pragma unroll
      for (int q = 0; q < 4; ++q) {
        int row = w * 16 + lg * 4 + q;
        h1[row * HS + col] = bf1(fmaxf(acc[m][q] + bh, 0.f));
      }
    }
  }
  __syncthreads();   // h1 ready

  // ---- GEMM2: h1 @ wo (wo rows k>=150 are zero -> aliased cols harmless)
  f32x4 acc2 = (f32x4){0.f, 0.f, 0.f, 0.f};
  #pragma unroll
  for (int ks = 0; ks < 5; ++ks) {
    short8 a = *(const short8*)(h1 + (w * 16 + lr) * HS + ks * 32 + lg * 8);
    short8 bfw = *(const short8*)(wo + lr * KP + ks * 32 + lg * 8);
    acc2 = __builtin_amdgcn_mfma_f32_16x16x32_bf16(a, bfw, acc2, 0, 0, 0);
  }
  __syncthreads();   // all h1 reads done -> out_s region free

  // ---- epilogue
  float ssi = ss[b * KK + i];
  if (lr < LL) {
    float bo = b_out[lr];
    #pragma unroll
    for (int q = 0; q < 4; ++q) {
      int row = w * 16 + lg * 4 + q;
      out_s[row * 12 + lr] = acc2[q] + bo + ssi + ssj_s[row];
    }
  }
  __syncthreads();
  if (!WPT) {
    size_t base = ((size_t)(b * KK + i) * KK + j0) * LL;
    for (int idx = t; idx < 64 * LL; idx += 256) {
      int j = idx / LL, ll2 = idx - j * LL;
      rel[base + idx] = out_s[j * 12 + ll2];
    }
  } else {
    for (int idx = t; idx < 64 * LL; idx += 256) {
      int j = idx / LL, ll2 = idx - j * LL;
      float v = fmaxf(out_s[j * 12 + ll2], 0.f) * m_s[j];
      probsT[(((size_t)(b * LL + ll2)) * KK + j0 + j) * KK + i] = bf1(v);
    }
  }
}

// ---------------- ctxt via MFMA (bf16-only output; d-tile 32 -> 384 blocks) ----------------
__global__ __launch_bounds__(256) void k_ctxt_mfma(
    const short* __restrict__ probsT, const short* __restrict__ updT,
    const float* __restrict__ a_w, const float* __restrict__ span_len,
    short* __restrict__ ctxbf)
{
  int bidx = blockIdx.x;              // B * 8 * 24 = 384
  int b = bidx / 192;
  int r = bidx - b * 192;
  int jt = r / 24, dt = r - jt * 24;
  int j0 = jt * 32, d0 = dt * 32;

  __shared__ short Bs[32][BPAD];
  __shared__ short As[32][BPAD];

  int t = threadIdx.x, l = t & 63, w = t >> 6, lr = l & 15, lg = l >> 4;
  int wr = w >> 1, wc = w & 1;

  for (int s = 0; s < 4; ++s) {
    int idx = t + s * 256;
    int row = idx >> 5, c = idx & 31;
    *(short8*)&Bs[row][c * 8] =
        *(const short8*)(updT + ((size_t)(b * DD + d0 + row)) * KK + c * 8);
  }

  short8 pa[4];
  #pragma unroll
  for (int s = 0; s < 4; ++s) {
    int idx = t + s * 256;
    int row = idx >> 5, c = idx & 31;
    pa[s] = *(const short8*)(probsT + (((size_t)(b * LL + 0)) * KK + j0 + row) * KK + c * 8);
  }

  f32x4 accF = (f32x4){0.f, 0.f, 0.f, 0.f};

  for (int ll = 0; ll < LL; ++ll) {
    __syncthreads();
    #pragma unroll
    for (int s = 0; s < 4; ++s) {
      int idx = t + s * 256;
      int row = idx >> 5, c = idx & 31;
      *(short8*)&As[row][c * 8] = pa[s];
    }
    if (ll + 1 < LL) {
      #pragma unroll
      for (int s = 0; s < 4; ++s) {
        int idx = t + s * 256;
        int row = idx >> 5, c = idx & 31;
        pa[s] = *(const short8*)(probsT + (((size_t)(b * LL + ll + 1)) * KK + j0 + row) * KK + c * 8);
      }
    }
    float awl = a_w[ll * DD + d0 + wc * 16 + lr];
    __syncthreads();

    f32x4 accL = (f32x4){0.f, 0.f, 0.f, 0.f};
    #pragma unroll
    for (int ks = 0; ks < 8; ++ks) {
      short8 a = *(short8*)&As[wr * 16 + lr][ks * 32 + lg * 8];
      short8 bf = *(short8*)&Bs[wc * 16 + lr][ks * 32 + lg * 8];
      accL = __builtin_amdgcn_mfma_f32_16x16x32_bf16(a, bf, accL, 0, 0, 0);
    }
    #pragma unroll
    for (int q = 0; q < 4; ++q)
      accF[q] = fmaf(awl, accL[q], accF[q]);
  }

  float inv = 1.f / span_len[b];
  int rowb = j0 + wr * 16 + lg * 4;
  int col = d0 + wc * 16 + lr;
  #pragma unroll
  for (int q = 0; q < 4; ++q) {
    size_t off = (size_t)(b * KK + rowb + q) * DD + col;
    ctxbf[off] = bf1(accF[q] * inv);
  }
}

// ---------------- gate via MFMA (K-step 128, bf16 ctxt blend, optional fused scatter) ----------------
template <bool LAST>
__global__ __launch_bounds__(256) void k_gate_mfma(
    const short* __restrict__ updbf, const short* __restrict__ ctxbf,
    const short* __restrict__ gwt, const float* __restrict__ gate_b,
    const float* __restrict__ updr, float* __restrict__ updw,
    short* __restrict__ nxtbf, short* __restrict__ updT,
    const int* __restrict__ prune, const float* __restrict__ span_len,
    float* __restrict__ out_all)
{
  int rb = blockIdx.x / 12, cb = blockIdx.x - rb * 12;
  int row0 = rb * 32, col0 = cb * 64;
  __shared__ short As[32][GWP];
  __shared__ short Bs[64][GWP];
  int t = threadIdx.x, l = t & 63, w = t >> 6, lr = l & 15, lg = l >> 4;
  int wr = w >> 1, wc = w & 1;

  f32x4 acc[2];
  acc[0] = (f32x4){0.f, 0.f, 0.f, 0.f};
  acc[1] = (f32x4){0.f, 0.f, 0.f, 0.f};

  short8 pa[2], pb[4];
  #pragma unroll
  for (int s = 0; s < 2; ++s) {
    int idx = t + s * 256;
    pa[s] = *(const short8*)(updbf + (size_t)(row0 + (idx >> 4)) * DD + (idx & 15) * 8);
  }
  #pragma unroll
  for (int s = 0; s < 4; ++s) {
    int idx = t + s * 256;
    pb[s] = *(const short8*)(gwt + (size_t)(col0 + (idx >> 4)) * (2 * DD) + (idx & 15) * 8);
  }

  for (int ph = 0; ph < 12; ++ph) {
    __syncthreads();
    #pragma unroll
    for (int s = 0; s < 2; ++s) {
      int idx = t + s * 256;
      *(short8*)&As[idx >> 4][(idx & 15) * 8] = pa[s];
    }
    #pragma unroll
    for (int s = 0; s < 4; ++s) {
      int idx = t + s * 256;
      *(short8*)&Bs[idx >> 4][(idx & 15) * 8] = pb[s];
    }
    if (ph + 1 < 12) {
      int k0 = (ph + 1) * 128;
      #pragma unroll
      for (int s = 0; s < 2; ++s) {
        int idx = t + s * 256;
        int ka = k0 + (idx & 15) * 8;
        const short* asrc = (ka < DD) ? (updbf + (size_t)(row0 + (idx >> 4)) * DD + ka)
                                      : (ctxbf + (size_t)(row0 + (idx >> 4)) * DD + ka - DD);
        pa[s] = *(const short8*)asrc;
      }
      #pragma unroll
      for (int s = 0; s < 4; ++s) {
        int idx = t + s * 256;
        pb[s] = *(const short8*)(gwt + (size_t)(col0 + (idx >> 4)) * (2 * DD) + k0 + (idx & 15) * 8);
      }
    }
    __syncthreads();
    #pragma unroll
    for (int ksub = 0; ksub < 4; ++ksub) {
      short8 a = *(short8*)&As[wr * 16 + lr][ksub * 32 + lg * 8];
      #pragma unroll
      for (int nt = 0; nt < 2; ++nt) {
        short8 bf = *(short8*)&Bs[wc * 32 + nt * 16 + lr][ksub * 32 + lg * 8];
        acc[nt] = __builtin_amdgcn_mfma_f32_16x16x32_bf16(a, bf, acc[nt], 0, 0, 0);
      }
    }
  }
  int rowb = row0 + wr * 16 + lg * 4;
  int bb = rowb >> 8, ii = rowb & 255;
  #pragma unroll
  for (int nt = 0; nt < 2; ++nt) {
    int col = col0 + wc * 32 + nt * 16 + lr;
    float gb = gate_b[col];
    s16x4 tw;
    #pragma unroll
    for (int q = 0; q < 4; ++q) {
      size_t off = (size_t)(rowb + q) * DD + col;
      float x = acc[nt][q] + gb;
      float g = 1.f / (1.f + expf(-x));
      float cv = ubf(ctxbf[off]);
      float o = g * updr[off] + (1.f - g) * cv;
      updw[off] = o;
      short bv = bf1(o);
      nxtbf[off] = bv;
      tw[q] = bv;
      if (LAST) {
        int iq = ii + q;
        if ((float)iq < span_len[bb]) {
          int dst = prune[bb * KK + iq];
          out_all[((size_t)(bb * NN + dst)) * DD + col] = o;
        }
      }
    }
    *(s16x4*)(updT + ((size_t)(bb * DD + col)) * KK + ii) = tw;
  }
}

extern "C" void kernel_launch(void* const* d_in, const int* in_sizes, int n_in,
                              void* d_out, int out_size, void* d_ws, size_t ws_size,
                              hipStream_t stream)
{
  (void)in_sizes; (void)n_in; (void)out_size; (void)ws_size;
  const float* all_span = (const float*)d_in[0];
  const float* upd_in   = (const float*)d_in[1];
  const float* mask     = (const float*)d_in[2];
  const float* span_len = (const float*)d_in[3];
  const int*   span_beg = (const int*)d_in[4];
  const int*   prune    = (const int*)d_in[6];
  const float* w_left   = (const float*)d_in[7];
  const float* b_left   = (const float*)d_in[8];
  const float* w_right  = (const float*)d_in[9];
  const float* b_right  = (const float*)d_in[10];
  const float* dist_emb = (const float*)d_in[11];
  const float* w_h      = (const float*)d_in[12];
  const float* b_h      = (const float*)d_in[13];
  const float* w_out    = (const float*)d_in[14];
  const float* b_out    = (const float*)d_in[15];
  const float* a_w      = (const float*)d_in[16];
  const float* gate_w   = (const float*)d_in[17];
  const float* gate_b   = (const float*)d_in[18];
  const float* pr_w     = (const float*)d_in[19];
  const float* pr_b     = (const float*)d_in[20];

  float* out_all = (float*)d_out;
  float* out_upd = out_all + (size_t)BB * NN * DD;
  float* out_rel = out_upd + (size_t)BB * KK * DD;

  float* ws     = (float*)d_ws;
  float* left   = ws;
  float* right  = left + (size_t)BB * KK * HH;
  float* ssv    = right + (size_t)BB * KK * HH + 64;
  short* wt_bf  = (short*)(ssv + (size_t)BB * KK);
  short* wo_bf  = wt_bf + KP * KP;
  short* updbf0 = wo_bf + 16 * KP;
  short* updbf1 = updbf0 + (size_t)BB * KK * DD;
  short* ctxbf  = updbf1 + (size_t)BB * KK * DD;
  short* gwt    = ctxbf + (size_t)BB * KK * DD;
  short* wlrt   = gwt + (size_t)DD * 2 * DD;
  short* probsT = wlrt + (size_t)2 * KP * DD;
  short* updT   = probsT + (size_t)BB * LL * KK * KK;

  hipMemcpyAsync(out_all, all_span, sizeof(float) * (size_t)BB * NN * DD,
                 hipMemcpyDeviceToDevice, stream);
  k_pre<<<PRE_NB, 256, 0, stream>>>(w_h, w_out, wt_bf, wo_bf, upd_in, updbf0,
                                    gate_w, gwt, w_left, w_right, wlrt, updT);

  k_projss<<<144, 256, 0, stream>>>(updbf0, wlrt, b_left, b_right, upd_in,
                                    pr_w, pr_b, left, right, ssv);
  k_pair_mfma<true><<<BB * KK * 4, 256, 0, stream>>>(
      left, right, ssv, span_beg, dist_emb, wt_bf, wo_bf, b_h, b_out, mask,
      out_rel, probsT);

  for (int p = 0; p < 2; ++p) {
    short* cur_bf = (p == 0) ? updbf0 : updbf1;
    short* nxt_bf = (p == 0) ? updbf1 : updbf0;
    const float* updr = (p == 0) ? upd_in : out_upd;
    k_ctxt_mfma<<<BB * 8 * 24, 256, 0, stream>>>(probsT, updT, a_w, span_len, ctxbf);
    if (p == 0) {
      k_gate_mfma<false><<<16 * 12, 256, 0, stream>>>(
          cur_bf, ctxbf, gwt, gate_b, updr, out_upd, nxt_bf, updT,
          prune, span_len, out_all);
    } else {
      k_gate_mfma<true><<<16 * 12, 256, 0, stream>>>(
          cur_bf, ctxbf, gwt, gate_b, updr, out_upd, nxt_bf, updT,
          prune, span_len, out_all);
    }
    k_projss<<<144, 256, 0, stream>>>(nxt_bf, wlrt, b_left, b_right, out_upd,
                                      pr_w, pr_b, left, right, ssv);
    if (p == 0) {
      k_pair_mfma<true><<<BB * KK * 4, 256, 0, stream>>>(
          left, right, ssv, span_beg, dist_emb, wt_bf, wo_bf, b_h, b_out, mask,
          out_rel, probsT);
    } else {
      k_pair_mfma<false><<<BB * KK * 4, 256, 0, stream>>>(
          left, right, ssv, span_beg, dist_emb, wt_bf, wo_bf, b_h, b_out, mask,
          out_rel, probsT);
    }
  }
}

// Round 21
// 186.014 us; speedup vs baseline: 1.0760x; 1.0025x over previous
//
#include <hip/hip_runtime.h>
#include <hip/hip_bf16.h>
#include <math.h>

#define BB 2
#define NN 2048
#define KK 256
#define DD 768
#define HH 150
#define LL 11
#define NBINS 10

#define KP 160          // padded K/N for MFMA tiles
#define HS 160          // h1 row stride in shorts (FULL fragment width; no OOB reads)
#define WP 40           // staged k-slice row stride in shorts (proj)
#define GWP 136         // gate K-step-128 row stride in shorts
#define BPAD 264        // 256-i row stride in shorts (ctxt staging)

typedef __attribute__((ext_vector_type(8))) short short8;
typedef __attribute__((ext_vector_type(4))) short s16x4;
typedef __attribute__((ext_vector_type(4))) float f32x4;

#define AS_GLOBAL const __attribute__((address_space(1))) void*
#define AS_LDS __attribute__((address_space(3))) void*

__device__ inline unsigned bf2u(float lo, float hi) {
  union { __hip_bfloat162 b; unsigned u; } cv;
  cv.b = __float22bfloat162_rn(make_float2(lo, hi));
  return cv.u;
}
__device__ inline short bf1(float x) {
  union { __hip_bfloat16 b; short s; } cv;
  cv.b = __float2bfloat16(x);
  return cv.s;
}
__device__ inline float ubf(short b) {          // bf16 bits -> f32 (exact)
  return __uint_as_float(((unsigned)(unsigned short)b) << 16);
}

// ---------------- merged one-shot prep ----------------
#define PRE_PREP 110
#define PRE_CVT  192
#define PRE_TRGW 1152
#define PRE_TRWLR 240
#define PRE_TRUPD 384
#define PRE_NB (PRE_PREP + PRE_CVT + PRE_TRGW + PRE_TRWLR + PRE_TRUPD)

__global__ __launch_bounds__(256) void k_pre(
    const float* __restrict__ w_h, const float* __restrict__ w_out,
    short* __restrict__ wt, short* __restrict__ wo,
    const float* __restrict__ upd_in, short* __restrict__ updbf,
    const float* __restrict__ gate_w, short* __restrict__ gwt,
    const float* __restrict__ w_left, const float* __restrict__ w_right,
    short* __restrict__ wlrt, short* __restrict__ updT)
{
  __shared__ float tile[32][33];
  int bid = blockIdx.x;
  int t = threadIdx.x;

  if (bid < PRE_PREP) {
    int idx = bid * 256 + t;
    if (idx < KP * KP) {
      int n = idx / KP, k = idx - n * KP;
      float v = (n < HH && k < HH) ? w_h[k * HH + n] : 0.f;
      wt[idx] = bf1(v);
    }
    int idx2 = idx - KP * KP;
    if (idx2 >= 0 && idx2 < 16 * KP) {
      int n = idx2 / KP, k = idx2 - n * KP;
      float v = (n < LL && k < HH) ? w_out[k * LL + n] : 0.f;
      wo[idx2] = bf1(v);
    }
    return;
  }
  bid -= PRE_PREP;
  if (bid < PRE_CVT) {
    int idx = (bid * 256 + t) * 8;
    const float4* s4 = (const float4*)(upd_in + idx);
    float4 a = s4[0], c = s4[1];
    int4 pk;
    pk.x = (int)bf2u(a.x, a.y);
    pk.y = (int)bf2u(a.z, a.w);
    pk.z = (int)bf2u(c.x, c.y);
    pk.w = (int)bf2u(c.z, c.w);
    *(int4*)(updbf + idx) = pk;
    return;
  }
  bid -= PRE_CVT;
  if (bid < PRE_TRGW) {
    int kt = bid % 48, nt = bid / 48;
    int m0 = kt * 32, n0 = nt * 32;
    int tx = t & 31, ty = t >> 5;
    #pragma unroll
    for (int r = 0; r < 4; ++r)
      tile[ty + r * 8][tx] = gate_w[(size_t)(m0 + ty + r * 8) * DD + n0 + tx];
    __syncthreads();
    #pragma unroll
    for (int r = 0; r < 4; ++r)
      gwt[(size_t)(n0 + ty + r * 8) * (2 * DD) + m0 + tx] = bf1(tile[tx][ty + r * 8]);
    return;
  }
  bid -= PRE_TRGW;
  if (bid < PRE_TRWLR) {
    int kt = bid % 24, nt = bid / 24;
    int k0 = kt * 32, n0 = nt * 32;
    const float* src = (n0 >= KP) ? w_right : w_left;
    int col0 = n0 - (n0 >= KP ? KP : 0);
    int tx = t & 31, ty = t >> 5;
    #pragma unroll
    for (int r = 0; r < 4; ++r) {
      int col = col0 + tx;
      tile[ty + r * 8][tx] = (col < HH) ? src[(size_t)(k0 + ty + r * 8) * HH + col] : 0.f;
    }
    __syncthreads();
    #pragma unroll
    for (int r = 0; r < 4; ++r)
      wlrt[(size_t)(n0 + ty + r * 8) * DD + k0 + tx] = bf1(tile[tx][ty + r * 8]);
    return;
  }
  bid -= PRE_TRWLR;
  {
    int b = bid / 192;
    int r = bid - b * 192;
    int it = r & 7, dt = r >> 3;
    int i0 = it * 32, d0 = dt * 32;
    int tx = t & 31, ty = t >> 5;
    #pragma unroll
    for (int rr = 0; rr < 4; ++rr)
      tile[ty + rr * 8][tx] = upd_in[(size_t)(b * KK + i0 + ty + rr * 8) * DD + d0 + tx];
    __syncthreads();
    #pragma unroll
    for (int rr = 0; rr < 4; ++rr)
      updT[(size_t)(b * DD + d0 + ty + rr * 8) * KK + i0 + tx] = bf1(tile[tx][ty + rr * 8]);
  }
}

// ---------------- proj via MFMA + fused pruner-score blocks ----------------
__global__ __launch_bounds__(256) void k_projss(
    const short* __restrict__ updbf, const short* __restrict__ wlrt,
    const float* __restrict__ b_left, const float* __restrict__ b_right,
    const float* __restrict__ updf, const float* __restrict__ pr_w,
    const float* __restrict__ pr_b,
    float* __restrict__ left, float* __restrict__ right, float* __restrict__ ssv)
{
  __shared__ short As[64][WP];
  __shared__ short Bs[KP][WP];
  int bidx = blockIdx.x;
  int t = threadIdx.x;

  if (bidx >= 16) {     // pruner-score blocks
    int row = (bidx - 16) * 4 + (t >> 6);
    int l = t & 63;
    float s = 0.f;
    for (int d = l; d < DD; d += 64) s = fmaf(updf[(size_t)row * DD + d], pr_w[d], s);
    #pragma unroll
    for (int off = 32; off > 0; off >>= 1) s += __shfl_down(s, off);
    if (l == 0) ssv[row] = s + pr_b[0];
    return;
  }

  int rbk = bidx >> 1, half = bidx & 1;
  int row0 = rbk * 64;
  const short* wsrc = wlrt + (size_t)half * KP * DD;
  int l = t & 63, w = t >> 6, lr = l & 15, lg = l >> 4;
  int ar = t >> 2, ac = t & 3;
  int i1 = t + 256, i2 = t + 512;
  f32x4 acc[10];
  #pragma unroll
  for (int nt = 0; nt < 10; ++nt) acc[nt] = (f32x4){0.f, 0.f, 0.f, 0.f};

  short8 pa, pb0, pb1, pb2 = {};
  pa  = *(const short8*)(updbf + (size_t)(row0 + ar) * DD + ac * 8);
  pb0 = *(const short8*)(wsrc + (size_t)(t >> 2) * DD + (t & 3) * 8);
  pb1 = *(const short8*)(wsrc + (size_t)(i1 >> 2) * DD + (i1 & 3) * 8);
  if (i2 < 640) pb2 = *(const short8*)(wsrc + (size_t)(i2 >> 2) * DD + (i2 & 3) * 8);

  for (int ks = 0; ks < 24; ++ks) {
    __syncthreads();
    *(short8*)&As[ar][ac * 8] = pa;
    *(short8*)&Bs[t >> 2][(t & 3) * 8] = pb0;
    *(short8*)&Bs[i1 >> 2][(i1 & 3) * 8] = pb1;
    if (i2 < 640) *(short8*)&Bs[i2 >> 2][(i2 & 3) * 8] = pb2;
    __syncthreads();
    if (ks + 1 < 24) {
      int k0 = (ks + 1) * 32;
      pa  = *(const short8*)(updbf + (size_t)(row0 + ar) * DD + k0 + ac * 8);
      pb0 = *(const short8*)(wsrc + (size_t)(t >> 2) * DD + k0 + (t & 3) * 8);
      pb1 = *(const short8*)(wsrc + (size_t)(i1 >> 2) * DD + k0 + (i1 & 3) * 8);
      if (i2 < 640) pb2 = *(const short8*)(wsrc + (size_t)(i2 >> 2) * DD + k0 + (i2 & 3) * 8);
    }
    short8 a = *(short8*)&As[w * 16 + lr][lg * 8];
    #pragma unroll
    for (int nt = 0; nt < 10; ++nt) {
      short8 b = *(short8*)&Bs[nt * 16 + lr][lg * 8];
      acc[nt] = __builtin_amdgcn_mfma_f32_16x16x32_bf16(a, b, acc[nt], 0, 0, 0);
    }
  }
  const float* bias = half ? b_right : b_left;
  float* dst = half ? right : left;
  int rowb = row0 + w * 16 + lg * 4;
  #pragma unroll
  for (int nt = 0; nt < 10; ++nt) {
    int col = nt * 16 + lr;
    if (col < HH) {
      float bv = bias[col];
      #pragma unroll
      for (int q = 0; q < 4; ++q)
        dst[(size_t)(rowb + q) * HH + col] = acc[nt][q] + bv;
    }
  }
}

// ---------------- pair scores via MFMA (v12: single-buffer wt, h1 stride 160, race-free) ----------------
template <bool WPT>
__global__ __launch_bounds__(256, 4) void k_pair_mfma(
    const float* __restrict__ left, const float* __restrict__ right,
    const float* __restrict__ ss, const int* __restrict__ span_begin,
    const float* __restrict__ demb,
    const short* __restrict__ wt, const short* __restrict__ wo,
    const float* __restrict__ b_h, const float* __restrict__ b_out,
    const float* __restrict__ mask,
    float* __restrict__ rel, short* __restrict__ probsT)
{
  int bid = blockIdx.x;
  int b  = bid >> 10;
  int r2 = bid & 1023;
  int i  = r2 >> 2;
  int j0 = (r2 & 3) * 64;

  // 20480 B union: [wt slab 10240 | ld_s 6400 @10240] -> h1 [64][160] -> out_s f32[64][12]
  __shared__ int4 smem[1280];
  __shared__ float ssj_s[64];
  __shared__ float m_s[64];
  __shared__ int   bins[64];

  short* wtslab = (short*)smem;
  float* ld_s   = (float*)((char*)smem + 10240);
  short* h1     = (short*)smem;
  float* out_s  = (float*)smem;

  int t = threadIdx.x;
  int l = t & 63, w = t >> 6;
  int lr = l & 15, lg = l >> 4;

  auto dma_wt = [&](int s) {
    const short* src = wt + s * 5120;
    #pragma unroll
    for (int c = 0; c < 3; ++c) {
      int idx = t + c * 256;
      if (idx < 640)
        __builtin_amdgcn_global_load_lds((AS_GLOBAL)(src + idx * 8),
                                         (AS_LDS)(wtslab + idx * 8), 16, 0, 0);
    }
  };

  // ---- phase 0: DMA slice 0; stage ld_s (left_i+demb, zero-padded), bins/ssj/mask
  dma_wt(0);
  int sbi = span_begin[b * KK + i];
  if (t < 64) {
    int d = span_begin[b * KK + j0 + t] - sbi; d = d < 0 ? -d : d;
    bins[t] = d > NBINS - 1 ? NBINS - 1 : d;
    ssj_s[t] = ss[b * KK + j0 + t];
    if (WPT) m_s[t] = mask[((size_t)(b * KK + i)) * KK + j0 + t];
  }
  {
    const float* lrow = left + (size_t)(b * KK + i) * HH;
    for (int idx = t; idx < NBINS * KP; idx += 256) {
      int bn = idx / KP, k = idx - bn * KP;
      ld_s[bn * KP + k] = (k < HH) ? (lrow[k] + demb[bn * HH + k]) : 0.f;
    }
  }
  __syncthreads();   // DMA(0) drained + ld_s/bins ready

  // ---- build A-fragments in registers
  int jr = w * 16 + lr;
  int binr = bins[jr];
  const float* rrow = right + (size_t)(b * KK + j0 + jr) * HH;
  const float* ldr = ld_s + binr * KP;
  short8 afr[5];
  #pragma unroll
  for (int ks = 0; ks < 5; ++ks) {
    unsigned pk[4];
    #pragma unroll
    for (int e = 0; e < 4; ++e) {
      int k = ks * 32 + lg * 8 + e * 2;
      float2 r2v = (k < HH - 1) ? *(const float2*)(rrow + k) : make_float2(0.f, 0.f);
      float2 lv = *(const float2*)(ldr + k);
      float v0 = fmaxf(lv.x + r2v.x, 0.f);
      float v1 = fmaxf(lv.y + r2v.y, 0.f);
      pk[e] = bf2u(v0, v1);
    }
    int4 tmp; tmp.x = (int)pk[0]; tmp.y = (int)pk[1]; tmp.z = (int)pk[2]; tmp.w = (int)pk[3];
    afr[ks] = *(short8*)&tmp;
  }

  // ---- GEMM1: 5 slices, single-buffered (TLP hides the DMA latency)
  f32x4 acc[10];
  #pragma unroll
  for (int m = 0; m < 10; ++m) acc[m] = (f32x4){0.f, 0.f, 0.f, 0.f};

  #pragma unroll
  for (int s = 0; s < 5; ++s) {
    if (s > 0) {
      __syncthreads();              // prior slice reads done
      dma_wt(s);
      __syncthreads();              // DMA drained
    }
    #pragma unroll
    for (int ks = 0; ks < 5; ++ks) {
      short8 a = afr[ks];
      #pragma unroll
      for (int ntp = 0; ntp < 2; ++ntp) {
        short8 bf = *(const short8*)(wtslab + (ntp * 16 + lr) * KP + ks * 32 + lg * 8);
        acc[s * 2 + ntp] = __builtin_amdgcn_mfma_f32_16x16x32_bf16(a, bf, acc[s * 2 + ntp], 0, 0, 0);
      }
    }
  }
  __syncthreads();   // wt + ld_s reads done -> h1 region free

  // ---- h1 = relu(acc + b_h) -> bf16, stride 160, FULL writes (cols>=150 are exact zeros)
  #pragma unroll
  for (int m = 0; m < 10; ++m) {
    int col = (m >> 1) * 32 + (m & 1) * 16 + lr;
    float bh = (col < HH) ? b_h[col] : 0.f;
    #pragma unroll
    for (int q = 0; q < 4; ++q) {
      int row = w * 16 + lg * 4 + q;
      h1[row * HS + col] = bf1(fmaxf(acc[m][q] + bh, 0.f));
    }
  }
  __syncthreads();   // h1 ready

  // ---- GEMM2: h1 @ wo (reads up to col 159: all initialized, finite)
  f32x4 acc2 = (f32x4){0.f, 0.f, 0.f, 0.f};
  #pragma unroll
  for (int ks = 0; ks < 5; ++ks) {
    short8 a = *(const short8*)(h1 + (w * 16 + lr) * HS + ks * 32 + lg * 8);
    short8 bfw = *(const short8*)(wo + lr * KP + ks * 32 + lg * 8);
    acc2 = __builtin_amdgcn_mfma_f32_16x16x32_bf16(a, bfw, acc2, 0, 0, 0);
  }
  __syncthreads();   // all h1 reads done -> out_s region free

  // ---- epilogue
  float ssi = ss[b * KK + i];
  if (lr < LL) {
    float bo = b_out[lr];
    #pragma unroll
    for (int q = 0; q < 4; ++q) {
      int row = w * 16 + lg * 4 + q;
      out_s[row * 12 + lr] = acc2[q] + bo + ssi + ssj_s[row];
    }
  }
  __syncthreads();
  if (!WPT) {
    size_t base = ((size_t)(b * KK + i) * KK + j0) * LL;
    for (int idx = t; idx < 64 * LL; idx += 256) {
      int j = idx / LL, ll2 = idx - j * LL;
      rel[base + idx] = out_s[j * 12 + ll2];
    }
  } else {
    for (int idx = t; idx < 64 * LL; idx += 256) {
      int j = idx / LL, ll2 = idx - j * LL;
      float v = fmaxf(out_s[j * 12 + ll2], 0.f) * m_s[j];
      probsT[(((size_t)(b * LL + ll2)) * KK + j0 + j) * KK + i] = bf1(v);
    }
  }
}

// ---------------- ctxt via MFMA (bf16-only output; d-tile 32 -> 384 blocks) ----------------
__global__ __launch_bounds__(256) void k_ctxt_mfma(
    const short* __restrict__ probsT, const short* __restrict__ updT,
    const float* __restrict__ a_w, const float* __restrict__ span_len,
    short* __restrict__ ctxbf)
{
  int bidx = blockIdx.x;              // B * 8 * 24 = 384
  int b = bidx / 192;
  int r = bidx - b * 192;
  int jt = r / 24, dt = r - jt * 24;
  int j0 = jt * 32, d0 = dt * 32;

  __shared__ short Bs[32][BPAD];
  __shared__ short As[32][BPAD];

  int t = threadIdx.x, l = t & 63, w = t >> 6, lr = l & 15, lg = l >> 4;
  int wr = w >> 1, wc = w & 1;

  for (int s = 0; s < 4; ++s) {
    int idx = t + s * 256;
    int row = idx >> 5, c = idx & 31;
    *(short8*)&Bs[row][c * 8] =
        *(const short8*)(updT + ((size_t)(b * DD + d0 + row)) * KK + c * 8);
  }

  short8 pa[4];
  #pragma unroll
  for (int s = 0; s < 4; ++s) {
    int idx = t + s * 256;
    int row = idx >> 5, c = idx & 31;
    pa[s] = *(const short8*)(probsT + (((size_t)(b * LL + 0)) * KK + j0 + row) * KK + c * 8);
  }

  f32x4 accF = (f32x4){0.f, 0.f, 0.f, 0.f};

  for (int ll = 0; ll < LL; ++ll) {
    __syncthreads();
    #pragma unroll
    for (int s = 0; s < 4; ++s) {
      int idx = t + s * 256;
      int row = idx >> 5, c = idx & 31;
      *(short8*)&As[row][c * 8] = pa[s];
    }
    if (ll + 1 < LL) {
      #pragma unroll
      for (int s = 0; s < 4; ++s) {
        int idx = t + s * 256;
        int row = idx >> 5, c = idx & 31;
        pa[s] = *(const short8*)(probsT + (((size_t)(b * LL + ll + 1)) * KK + j0 + row) * KK + c * 8);
      }
    }
    float awl = a_w[ll * DD + d0 + wc * 16 + lr];
    __syncthreads();

    f32x4 accL = (f32x4){0.f, 0.f, 0.f, 0.f};
    #pragma unroll
    for (int ks = 0; ks < 8; ++ks) {
      short8 a = *(short8*)&As[wr * 16 + lr][ks * 32 + lg * 8];
      short8 bf = *(short8*)&Bs[wc * 16 + lr][ks * 32 + lg * 8];
      accL = __builtin_amdgcn_mfma_f32_16x16x32_bf16(a, bf, accL, 0, 0, 0);
    }
    #pragma unroll
    for (int q = 0; q < 4; ++q)
      accF[q] = fmaf(awl, accL[q], accF[q]);
  }

  float inv = 1.f / span_len[b];
  int rowb = j0 + wr * 16 + lg * 4;
  int col = d0 + wc * 16 + lr;
  #pragma unroll
  for (int q = 0; q < 4; ++q) {
    size_t off = (size_t)(b * KK + rowb + q) * DD + col;
    ctxbf[off] = bf1(accF[q] * inv);
  }
}

// ---------------- gate via MFMA (K-step 128, bf16 ctxt blend, optional fused scatter) ----------------
template <bool LAST>
__global__ __launch_bounds__(256) void k_gate_mfma(
    const short* __restrict__ updbf, const short* __restrict__ ctxbf,
    const short* __restrict__ gwt, const float* __restrict__ gate_b,
    const float* __restrict__ updr, float* __restrict__ updw,
    short* __restrict__ nxtbf, short* __restrict__ updT,
    const int* __restrict__ prune, const float* __restrict__ span_len,
    float* __restrict__ out_all)
{
  int rb = blockIdx.x / 12, cb = blockIdx.x - rb * 12;
  int row0 = rb * 32, col0 = cb * 64;
  __shared__ short As[32][GWP];
  __shared__ short Bs[64][GWP];
  int t = threadIdx.x, l = t & 63, w = t >> 6, lr = l & 15, lg = l >> 4;
  int wr = w >> 1, wc = w & 1;

  f32x4 acc[2];
  acc[0] = (f32x4){0.f, 0.f, 0.f, 0.f};
  acc[1] = (f32x4){0.f, 0.f, 0.f, 0.f};

  short8 pa[2], pb[4];
  #pragma unroll
  for (int s = 0; s < 2; ++s) {
    int idx = t + s * 256;
    pa[s] = *(const short8*)(updbf + (size_t)(row0 + (idx >> 4)) * DD + (idx & 15) * 8);
  }
  #pragma unroll
  for (int s = 0; s < 4; ++s) {
    int idx = t + s * 256;
    pb[s] = *(const short8*)(gwt + (size_t)(col0 + (idx >> 4)) * (2 * DD) + (idx & 15) * 8);
  }

  for (int ph = 0; ph < 12; ++ph) {
    __syncthreads();
    #pragma unroll
    for (int s = 0; s < 2; ++s) {
      int idx = t + s * 256;
      *(short8*)&As[idx >> 4][(idx & 15) * 8] = pa[s];
    }
    #pragma unroll
    for (int s = 0; s < 4; ++s) {
      int idx = t + s * 256;
      *(short8*)&Bs[idx >> 4][(idx & 15) * 8] = pb[s];
    }
    if (ph + 1 < 12) {
      int k0 = (ph + 1) * 128;
      #pragma unroll
      for (int s = 0; s < 2; ++s) {
        int idx = t + s * 256;
        int ka = k0 + (idx & 15) * 8;
        const short* asrc = (ka < DD) ? (updbf + (size_t)(row0 + (idx >> 4)) * DD + ka)
                                      : (ctxbf + (size_t)(row0 + (idx >> 4)) * DD + ka - DD);
        pa[s] = *(const short8*)asrc;
      }
      #pragma unroll
      for (int s = 0; s < 4; ++s) {
        int idx = t + s * 256;
        pb[s] = *(const short8*)(gwt + (size_t)(col0 + (idx >> 4)) * (2 * DD) + k0 + (idx & 15) * 8);
      }
    }
    __syncthreads();
    #pragma unroll
    for (int ksub = 0; ksub < 4; ++ksub) {
      short8 a = *(short8*)&As[wr * 16 + lr][ksub * 32 + lg * 8];
      #pragma unroll
      for (int nt = 0; nt < 2; ++nt) {
        short8 bf = *(short8*)&Bs[wc * 32 + nt * 16 + lr][ksub * 32 + lg * 8];
        acc[nt] = __builtin_amdgcn_mfma_f32_16x16x32_bf16(a, bf, acc[nt], 0, 0, 0);
      }
    }
  }
  int rowb = row0 + wr * 16 + lg * 4;
  int bb = rowb >> 8, ii = rowb & 255;
  #pragma unroll
  for (int nt = 0; nt < 2; ++nt) {
    int col = col0 + wc * 32 + nt * 16 + lr;
    float gb = gate_b[col];
    s16x4 tw;
    #pragma unroll
    for (int q = 0; q < 4; ++q) {
      size_t off = (size_t)(rowb + q) * DD + col;
      float x = acc[nt][q] + gb;
      float g = 1.f / (1.f + expf(-x));
      float cv = ubf(ctxbf[off]);
      float o = g * updr[off] + (1.f - g) * cv;
      updw[off] = o;
      short bv = bf1(o);
      nxtbf[off] = bv;
      tw[q] = bv;
      if (LAST) {
        int iq = ii + q;
        if ((float)iq < span_len[bb]) {
          int dst = prune[bb * KK + iq];
          out_all[((size_t)(bb * NN + dst)) * DD + col] = o;
        }
      }
    }
    *(s16x4*)(updT + ((size_t)(bb * DD + col)) * KK + ii) = tw;
  }
}

extern "C" void kernel_launch(void* const* d_in, const int* in_sizes, int n_in,
                              void* d_out, int out_size, void* d_ws, size_t ws_size,
                              hipStream_t stream)
{
  (void)in_sizes; (void)n_in; (void)out_size; (void)ws_size;
  const float* all_span = (const float*)d_in[0];
  const float* upd_in   = (const float*)d_in[1];
  const float* mask     = (const float*)d_in[2];
  const float* span_len = (const float*)d_in[3];
  const int*   span_beg = (const int*)d_in[4];
  const int*   prune    = (const int*)d_in[6];
  const float* w_left   = (const float*)d_in[7];
  const float* b_left   = (const float*)d_in[8];
  const float* w_right  = (const float*)d_in[9];
  const float* b_right  = (const float*)d_in[10];
  const float* dist_emb = (const float*)d_in[11];
  const float* w_h      = (const float*)d_in[12];
  const float* b_h      = (const float*)d_in[13];
  const float* w_out    = (const float*)d_in[14];
  const float* b_out    = (const float*)d_in[15];
  const float* a_w      = (const float*)d_in[16];
  const float* gate_w   = (const float*)d_in[17];
  const float* gate_b   = (const float*)d_in[18];
  const float* pr_w     = (const float*)d_in[19];
  const float* pr_b     = (const float*)d_in[20];

  float* out_all = (float*)d_out;
  float* out_upd = out_all + (size_t)BB * NN * DD;
  float* out_rel = out_upd + (size_t)BB * KK * DD;

  float* ws     = (float*)d_ws;
  float* left   = ws;
  float* right  = left + (size_t)BB * KK * HH;
  float* ssv    = right + (size_t)BB * KK * HH + 64;
  short* wt_bf  = (short*)(ssv + (size_t)BB * KK);
  short* wo_bf  = wt_bf + KP * KP;
  short* updbf0 = wo_bf + 16 * KP;
  short* updbf1 = updbf0 + (size_t)BB * KK * DD;
  short* ctxbf  = updbf1 + (size_t)BB * KK * DD;
  short* gwt    = ctxbf + (size_t)BB * KK * DD;
  short* wlrt   = gwt + (size_t)DD * 2 * DD;
  short* probsT = wlrt + (size_t)2 * KP * DD;
  short* updT   = probsT + (size_t)BB * LL * KK * KK;

  hipMemcpyAsync(out_all, all_span, sizeof(float) * (size_t)BB * NN * DD,
                 hipMemcpyDeviceToDevice, stream);
  k_pre<<<PRE_NB, 256, 0, stream>>>(w_h, w_out, wt_bf, wo_bf, upd_in, updbf0,
                                    gate_w, gwt, w_left, w_right, wlrt, updT);

  k_projss<<<144, 256, 0, stream>>>(updbf0, wlrt, b_left, b_right, upd_in,
                                    pr_w, pr_b, left, right, ssv);
  k_pair_mfma<true><<<BB * KK * 4, 256, 0, stream>>>(
      left, right, ssv, span_beg, dist_emb, wt_bf, wo_bf, b_h, b_out, mask,
      out_rel, probsT);

  for (int p = 0; p < 2; ++p) {
    short* cur_bf = (p == 0) ? updbf0 : updbf1;
    short* nxt_bf = (p == 0) ? updbf1 : updbf0;
    const float* updr = (p == 0) ? upd_in : out_upd;
    k_ctxt_mfma<<<BB * 8 * 24, 256, 0, stream>>>(probsT, updT, a_w, span_len, ctxbf);
    if (p == 0) {
      k_gate_mfma<false><<<16 * 12, 256, 0, stream>>>(
          cur_bf, ctxbf, gwt, gate_b, updr, out_upd, nxt_bf, updT,
          prune, span_len, out_all);
    } else {
      k_gate_mfma<true><<<16 * 12, 256, 0, stream>>>(
          cur_bf, ctxbf, gwt, gate_b, updr, out_upd, nxt_bf, updT,
          prune, span_len, out_all);
    }
    k_projss<<<144, 256, 0, stream>>>(nxt_bf, wlrt, b_left, b_right, out_upd,
                                      pr_w, pr_b, left, right, ssv);
    if (p == 0) {
      k_pair_mfma<true><<<BB * KK * 4, 256, 0, stream>>>(
          left, right, ssv, span_beg, dist_emb, wt_bf, wo_bf, b_h, b_out, mask,
          out_rel, probsT);
    } else {
      k_pair_mfma<false><<<BB * KK * 4, 256, 0, stream>>>(
          left, right, ssv, span_beg, dist_emb, wt_bf, wo_bf, b_h, b_out, mask,
          out_rel, probsT);
    }
  }
}